// Round 12
// baseline (222.856 us; speedup 1.0000x reference)
//
#include <hip/hip_runtime.h>
#include <hip/hip_bf16.h>
#include <math.h>

#define C_IN 256
#define H_   64
#define W_   64
#define B_   8
#define COUT 256
#define HW   (H_*W_)

typedef float f32x4 __attribute__((ext_vector_type(4)));
typedef float f32x2 __attribute__((ext_vector_type(2)));
typedef short short8 __attribute__((ext_vector_type(8)));

static __device__ __forceinline__ int pack_bf16x2(float a, float b) {
    __hip_bfloat162 h = __float22bfloat162_rn(make_float2(a, b));
    union { __hip_bfloat162 h; int i; } u; u.h = h;
    return u.i;
}

// unpack bf16x2 word -> float2 (lo, hi)
static __device__ __forceinline__ f32x2 up2(int v) {
    union { int i; float f; } a, b;
    a.i = v << 16;
    b.i = v & 0xffff0000;
    f32x2 r; r[0] = a.f; r[1] = b.f;
    return r;
}

// LDS-only barrier: drains lgkmcnt (publishes ds_writes) but leaves VMEM
// prefetch loads in flight across the barrier. Proven correct in r6.
// Essential for the producer/consumer schedule: producers issue gathers
// in one half-stage and blend them in the next, across a barrier.
static __device__ __forceinline__ void wg_barrier_lds() {
    asm volatile("s_waitcnt lgkmcnt(0)" ::: "memory");
    __builtin_amdgcn_s_barrier();
    __builtin_amdgcn_sched_barrier(0);
}

// ---------------------------------------------------------------------------
// Prep: weights -> bf16, laid out so a wave's MFMA A-fragment is ONE coalesced
// 1KB global load (no LDS staging needed).
//   wR: (k*8+cblk*2+ks)*8192 + oblk*512 + q*128 + ol*8 + ce    (o in 0..255)
//   wO: (k*8+cblk*2+ks)*1024 + oblk*512 + q*128 + ol*8 + ce    (o in 0..31)
// ---------------------------------------------------------------------------
__global__ __launch_bounds__(256) void prep_weights_kernel(
    const float* __restrict__ ow, const float* __restrict__ dw,
    short* __restrict__ wR, short* __restrict__ wO)
{
    int blk = blockIdx.x;
    int k   = blk / 288;
    int row = blk % 288;
    int c   = threadIdx.x;
    int cblk = c >> 6, ks = (c >> 5) & 1, q = (c >> 3) & 3, ce = c & 7;
    union { float f; unsigned u; } a;
    if (row < 256) {
        int o = row;
        a.f = dw[(size_t)o * 2304 + c * 9 + k];
        unsigned r = (a.u + 0x7fffu + ((a.u >> 16) & 1u)) >> 16;
        size_t idx = (size_t)(k * 8 + cblk * 2 + ks) * 8192
                   + (size_t)(o >> 4) * 512 + q * 128 + (o & 15) * 8 + ce;
        wR[idx] = (short)r;
    } else {
        int o = row - 256;                 // 0..31
        a.f = (o < 18) ? ow[(size_t)o * 2304 + c * 9 + k] : 0.f;
        unsigned r = (a.u + 0x7fffu + ((a.u >> 16) & 1u)) >> 16;
        size_t idx = (size_t)(k * 8 + cblk * 2 + ks) * 1024
                   + (size_t)(o >> 4) * 512 + q * 128 + (o & 15) * 8 + ce;
        wO[idx] = (short)r;
    }
}

// ---------------------------------------------------------------------------
// Transpose x: NCHW fp32 -> NHWC bf16  xT[b][h][w][c]. One block per (b,h).
// ---------------------------------------------------------------------------
__global__ __launch_bounds__(256) void transpose_x_kernel(
    const float* __restrict__ x, unsigned short* __restrict__ xT)
{
    __shared__ float tile[64][257];
    const int tid = threadIdx.x;
    const int b = blockIdx.x >> 6, h = blockIdx.x & 63;
    const float* xb = x + ((size_t)b << 20) + h * 64;

#pragma unroll
    for (int pass = 0; pass < 16; ++pass) {
        int c  = pass * 16 + (tid >> 4);
        int w0 = (tid & 15) * 4;
        float4 v = *(const float4*)(xb + (size_t)c * 4096 + w0);
        tile[w0][c] = v.x; tile[w0 + 1][c] = v.y;
        tile[w0 + 2][c] = v.z; tile[w0 + 3][c] = v.w;
    }
    __syncthreads();

    int4* ob = (int4*)(xT + ((size_t)blockIdx.x << 14));
#pragma unroll
    for (int pass = 0; pass < 8; ++pass) {
        int idx = pass * 256 + tid;
        int w = idx >> 5, ch8 = idx & 31;
        const float* tr = &tile[w][ch8 * 8];
        int4 pk;
        pk.x = pack_bf16x2(tr[0], tr[1]);
        pk.y = pack_bf16x2(tr[2], tr[3]);
        pk.z = pack_bf16x2(tr[4], tr[5]);
        pk.w = pack_bf16x2(tr[6], tr[7]);
        ob[idx] = pk;
    }
}

// ---------------------------------------------------------------------------
// Offset conv via bf16 MFMA — ROW-TILE chunk-major (r10, kept).
// ---------------------------------------------------------------------------
__global__ __launch_bounds__(256, 2) void offset_mfma_kernel(
    const unsigned short* __restrict__ xT, const short* __restrict__ wO,
    float* __restrict__ offs)
{
    __shared__ int4 xtile[3 * 66 * 8];     // 25.3 KB

    const int tid = threadIdx.x;
    const int b   = blockIdx.x & 7;        // XCD pin
    const int ho  = blockIdx.x >> 3;

    const int wv = tid >> 6;
    const int ln = tid & 63;
    const int lo = ln & 15;
    const int quad = ln >> 4;

    f32x4 acc[2];
    acc[0] = (f32x4){0.f, 0.f, 0.f, 0.f};
    acc[1] = (f32x4){0.f, 0.f, 0.f, 0.f};

    const unsigned short* xbb = xT + ((size_t)b << 20);
    const int4 zero4 = {0, 0, 0, 0};

    const int srow = tid >> 6;             // 0..3
    const int spx  = tid & 63;
    const int syy  = ho + srow - 1;
    const bool svalid = (srow < 3) && (syy >= 0) && (syy < 64);
    const int syc  = min(max(syy, 0), 63);
    const unsigned short* sbase = xbb + (((size_t)(syc * 64 + spx)) << 8);
    const int sslot = spx + 1;

#define OLOAD(CH, G)                                                          \
    if (srow < 3) {                                                           \
        const int4* sp_ = (const int4*)(sbase + (CH));                        \
        _Pragma("unroll")                                                     \
        for (int j = 0; j < 8; ++j) G[j] = sp_[j];                            \
    }
#define OCOMMIT(G)                                                            \
    if (srow < 3) {                                                           \
        _Pragma("unroll")                                                     \
        for (int j = 0; j < 8; ++j)                                           \
            xtile[(srow * 66 + sslot) * 8 + (j ^ (sslot & 7))]                \
                = svalid ? G[j] : zero4;                                      \
    }

    auto mfmaC = [&](int chunk) {
        __builtin_amdgcn_s_setprio(1);
#pragma unroll
        for (int ky = 0; ky < 3; ++ky) {
#pragma unroll
            for (int kx = 0; kx < 3; ++kx) {
#pragma unroll
                for (int ks = 0; ks < 2; ++ks) {
                    int ps = wv * 16 + lo + kx;
                    int cslot = (ks * 4 + quad) ^ (ps & 7);
                    short8 bfr = *(const short8*)&xtile[(ky * 66 + ps) * 8 + cslot];
                    const short* wkb = wO
                        + (size_t)((ky * 3 + kx) * 8 + chunk * 2 + ks) * 1024
                        + ln * 8;
#pragma unroll
                    for (int t = 0; t < 2; ++t) {
                        short8 afr = *(const short8*)(wkb + t * 512);
                        acc[t] = __builtin_amdgcn_mfma_f32_16x16x32_bf16(
                            afr, bfr, acc[t], 0, 0, 0);
                    }
                }
            }
        }
        __builtin_amdgcn_s_setprio(0);
    };

    int4 ga[8], gb[8];
    OLOAD(0, ga);
    OCOMMIT(ga);
    if (srow == 3 && (tid & 63) < 6) {
        int idx = tid & 63;
        int row_ = idx >> 1, s_ = (idx & 1) * 65;
#pragma unroll
        for (int j = 0; j < 8; ++j) xtile[(row_ * 66 + s_) * 8 + j] = zero4;
    }
    __syncthreads();

    OLOAD(64, gb);
    __builtin_amdgcn_sched_barrier(0);
    mfmaC(0);
    __syncthreads();
    OCOMMIT(gb);
    __syncthreads();

    OLOAD(128, ga);
    __builtin_amdgcn_sched_barrier(0);
    mfmaC(1);
    __syncthreads();
    OCOMMIT(ga);
    __syncthreads();

    OLOAD(192, gb);
    __builtin_amdgcn_sched_barrier(0);
    mfmaC(2);
    __syncthreads();
    OCOMMIT(gb);
    __syncthreads();

    mfmaC(3);
#undef OLOAD
#undef OCOMMIT

#pragma unroll
    for (int t = 0; t < 2; ++t) {
#pragma unroll
        for (int r = 0; r < 4; ++r) {
            int o = t * 16 + quad * 4 + r;
            if (o < 18)
                offs[((size_t)b * 18 + o) * HW + ho * 64 + wv * 16 + lo] = acc[t][r];
        }
    }
}

// ---------------------------------------------------------------------------
// Deformable conv — PRODUCER/CONSUMER wave specialization. One block per
// (b,ho): grid 512, 512 threads = 8 waves. Waves 0-3 (producers): gather +
// blend + LDS write into a 4-deep bT ring, running 2 stages ahead. Waves
// 4-7 (consumers): ds_read + MFMA only (each wave 64o x 64px, acc[4][4]),
// A-frags prefetched 1 stage ahead from global. One lgkm-only barrier per
// half-stage = rendezvous, NOT phase-serializer: blend VALU and MFMA run
// concurrently on the same SIMDs (m114 co-issue).
// ---------------------------------------------------------------------------
struct afrag { short8 v[2][4]; };

__global__ __launch_bounds__(512, 2) void deform_mfma_kernel(
    const unsigned short* __restrict__ xT, const float* __restrict__ offs,
    const short* __restrict__ wR, float* __restrict__ y,
    float* __restrict__ sum_, float* __restrict__ sumsq_)
{
    __shared__ int4   meta_i[576];         // 9.2 KB
    __shared__ float4 meta_w[576];         // 9.2 KB
    __shared__ int4   bT[4][64 * 8];       // 32 KB ring

    const int tid = threadIdx.x;
    const int b   = blockIdx.x & 7;            // XCD pin
    const int ho  = blockIdx.x >> 3;

    for (int e = tid; e < 576; e += 512) {
        int kk  = e >> 6;
        int pxe = e & 63;
        float dy = offs[((size_t)b * 18 + 2 * kk)     * HW + ho * W_ + pxe];
        float dx = offs[((size_t)b * 18 + 2 * kk + 1) * HW + ho * W_ + pxe];
        float sy = (float)(ho - 1 + kk / 3) + dy;
        float sx = (float)(pxe - 1 + kk % 3) + dx;
        float y0f = floorf(sy), x0f = floorf(sx);
        float ly = sy - y0f, lx = sx - x0f;
        int y0 = (int)y0f, x0 = (int)x0f;
        int y1 = y0 + 1, x1 = x0 + 1;
        float wy0 = 1.f - ly, wx0 = 1.f - lx;
        bool vy0 = (y0 >= 0) & (y0 < H_), vy1 = (y1 >= 0) & (y1 < H_);
        bool vx0 = (x0 >= 0) & (x0 < W_), vx1 = (x1 >= 0) & (x1 < W_);
        int cy0 = min(max(y0, 0), H_ - 1), cy1 = min(max(y1, 0), H_ - 1);
        int cx0 = min(max(x0, 0), W_ - 1), cx1 = min(max(x1, 0), W_ - 1);
        int4 ii; float4 ww;
        ii.x = (cy0 * W_ + cx0) << 9;  ww.x = wy0 * wx0 * ((vy0 & vx0) ? 1.f : 0.f);
        ii.y = (cy0 * W_ + cx1) << 9;  ww.y = wy0 * lx  * ((vy0 & vx1) ? 1.f : 0.f);
        ii.z = (cy1 * W_ + cx0) << 9;  ww.z = ly  * wx0 * ((vy1 & vx0) ? 1.f : 0.f);
        ii.w = (cy1 * W_ + cx1) << 9;  ww.w = ly  * lx  * ((vy1 & vx1) ? 1.f : 0.f);
        meta_i[e] = ii;
        meta_w[e] = ww;
    }

    const int wave  = tid >> 6;            // 0..7
    const bool isP  = wave < 4;            // producer role

    // producer indices (threads 0..255)
    const int px = tid >> 2;               // 0..63
    const int cg = tid & 3;                // 16-ch group (32B = 2 int4)

    // consumer indices (threads 256..511)
    const int wv2  = wave - 4;             // 0..3: o-range wv2*64
    const int ln   = tid & 63;
    const int lo   = ln & 15;
    const int quad = ln >> 4;

    f32x4 acc[4][4];
#pragma unroll
    for (int t = 0; t < 4; ++t)
#pragma unroll
        for (int p = 0; p < 4; ++p)
            acc[t][p] = (f32x4){0.f, 0.f, 0.f, 0.f};

    const char* xbb = (const char*)(xT + ((size_t)b << 20) + cg * 16);

#define ISSUE_G(S, G0,G1,G2,G3,G4,G5,G6,G7)                                   \
    {                                                                         \
        int kn_ = (S) >> 2, cn_ = ((S) & 3) << 7;                             \
        int4 ii_ = meta_i[kn_ * 64 + px];                                     \
        const char* xc_ = xbb + cn_;                                          \
        const int4* pA_ = (const int4*)(xc_ + ii_.x);                         \
        const int4* pB_ = (const int4*)(xc_ + ii_.y);                         \
        const int4* pC_ = (const int4*)(xc_ + ii_.z);                         \
        const int4* pD_ = (const int4*)(xc_ + ii_.w);                         \
        G0 = pA_[0]; G1 = pA_[1];                                             \
        G2 = pB_[0]; G3 = pB_[1];                                             \
        G4 = pC_[0]; G5 = pC_[1];                                             \
        G6 = pD_[0]; G7 = pD_[1];                                             \
    }

#define ISSUE_A(S, AF)                                                        \
    {                                                                         \
        const short* wkb_ = wR + (size_t)((((S) >> 2) * 8 + ((S) & 3) * 2))   \
                          * 8192 + wv2 * 2048 + ln * 8;                       \
        _Pragma("unroll")                                                     \
        for (int ks_ = 0; ks_ < 2; ++ks_)                                     \
            _Pragma("unroll")                                                 \
            for (int t_ = 0; t_ < 4; ++t_)                                    \
                AF.v[ks_][t_] = *(const short8*)(wkb_ + ks_ * 8192 + t_ * 512);\
    }

#define BLEND_W(S, G0,G1,G2,G3,G4,G5,G6,G7)                                   \
    {                                                                         \
        int kn_ = (S) >> 2;                                                   \
        float4 w4_ = meta_w[kn_ * 64 + px];                                   \
        auto bl_ = [&](int av, int bv, int cv, int dv) -> int {               \
            f32x2 r_ = up2(av) * w4_.x + up2(bv) * w4_.y                      \
                     + up2(cv) * w4_.z + up2(dv) * w4_.w;                     \
            return pack_bf16x2(r_[0], r_[1]);                                 \
        };                                                                    \
        int4 o0_, o1_;                                                        \
        o0_.x = bl_(G0.x, G2.x, G4.x, G6.x);                                  \
        o0_.y = bl_(G0.y, G2.y, G4.y, G6.y);                                  \
        o0_.z = bl_(G0.z, G2.z, G4.z, G6.z);                                  \
        o0_.w = bl_(G0.w, G2.w, G4.w, G6.w);                                  \
        o1_.x = bl_(G1.x, G3.x, G5.x, G7.x);                                  \
        o1_.y = bl_(G1.y, G3.y, G5.y, G7.y);                                  \
        o1_.z = bl_(G1.z, G3.z, G5.z, G7.z);                                  \
        o1_.w = bl_(G1.w, G3.w, G5.w, G7.w);                                  \
        bT[(S) & 3][px * 8 + ((2 * cg)     ^ (px & 7))] = o0_;                \
        bT[(S) & 3][px * 8 + ((2 * cg + 1) ^ (px & 7))] = o1_;                \
    }

    auto mfmaStage = [&](int s, const afrag& AF) {
        const int buf = s & 3;
        __builtin_amdgcn_s_setprio(1);
#pragma unroll
        for (int ks = 0; ks < 2; ++ks) {
            int ch = ks * 4 + quad;
            short8 bfr[4];
#pragma unroll
            for (int p = 0; p < 4; ++p) {
                int pp = p * 16 + lo;
                bfr[p] = *(const short8*)&bT[buf][pp * 8 + (ch ^ (pp & 7))];
            }
#pragma unroll
            for (int t = 0; t < 4; ++t)
#pragma unroll
                for (int p = 0; p < 4; ++p)
                    acc[t][p] = __builtin_amdgcn_mfma_f32_16x16x32_bf16(
                        AF.v[ks][t], bfr[p], acc[t][p], 0, 0, 0);
        }
        __builtin_amdgcn_s_setprio(0);
    };

    int4 a0, a1, a2, a3, a4, a5, a6, a7;
    int4 b0, b1, b2, b3, b4, b5, b6, b7;
    afrag afrA, afrB;

    __syncthreads();                 // meta ready (full barrier, once)

    // prologue: producers fill buf0, issue G(1); consumers prefetch A(0)
    if (isP) {
        ISSUE_G(0, a0,a1,a2,a3,a4,a5,a6,a7);
        ISSUE_G(1, b0,b1,b2,b3,b4,b5,b6,b7);
        BLEND_W(0, a0,a1,a2,a3,a4,a5,a6,a7);
    } else {
        ISSUE_A(0, afrA);
    }
    wg_barrier_lds();

#pragma unroll 1
    for (int t = 0; t < 17; ++t) {
        int s = 2 * t;
        if (isP) {
            ISSUE_G(s + 2, a0,a1,a2,a3,a4,a5,a6,a7);
            __builtin_amdgcn_sched_barrier(0);
            BLEND_W(s + 1, b0,b1,b2,b3,b4,b5,b6,b7);
        } else {
            ISSUE_A(s + 1, afrB);
            __builtin_amdgcn_sched_barrier(0);
            mfmaStage(s, afrA);
        }
        wg_barrier_lds();
        if (isP) {
            ISSUE_G(s + 3, b0,b1,b2,b3,b4,b5,b6,b7);
            __builtin_amdgcn_sched_barrier(0);
            BLEND_W(s + 2, a0,a1,a2,a3,a4,a5,a6,a7);
        } else {
            ISSUE_A(s + 2, afrA);
            __builtin_amdgcn_sched_barrier(0);
            mfmaStage(s + 1, afrB);
        }
        wg_barrier_lds();
    }
    // tail: producers hold G(35) in b*, consumers hold A(34) in afrA
    if (isP) {
        BLEND_W(35, b0,b1,b2,b3,b4,b5,b6,b7);
    } else {
        ISSUE_A(35, afrB);
        __builtin_amdgcn_sched_barrier(0);
        mfmaStage(34, afrA);
    }
    wg_barrier_lds();
    if (!isP) mfmaStage(35, afrB);

#undef ISSUE_G
#undef ISSUE_A
#undef BLEND_W

    if (!isP) {
        float* yb = y + ((size_t)b << 20) + ho * 64;
#pragma unroll
        for (int t = 0; t < 4; ++t) {
#pragma unroll
            for (int r = 0; r < 4; ++r) {
                int o = wv2 * 64 + t * 16 + quad * 4 + r;
                float sv = 0.f, qv = 0.f;
#pragma unroll
                for (int p = 0; p < 4; ++p) {
                    float val = acc[t][p][r];
                    yb[(size_t)o * HW + p * 16 + lo] = val;
                    sv += val;
                    qv += val * val;
                }
#pragma unroll
                for (int m = 1; m <= 8; m <<= 1) {
                    sv += __shfl_xor(sv, m, 16);
                    qv += __shfl_xor(qv, m, 16);
                }
                if (lo == 0) {
                    atomicAdd(&sum_[b * COUT + o], sv);
                    atomicAdd(&sumsq_[b * COUT + o], qv);
                }
            }
        }
    }
}

// ---------------------------------------------------------------------------
// Channel attention (mean + unbiased std -> sigmoid) and scale.
// ---------------------------------------------------------------------------
__global__ __launch_bounds__(256) void attn_scale_kernel(
    const float* __restrict__ sum_, const float* __restrict__ sumsq_,
    float* __restrict__ y)
{
    int bo = blockIdx.x;
    float s = sum_[bo], q = sumsq_[bo];
    float mean = s * (1.f / 4096.f);
    float var  = (q - s * s * (1.f / 4096.f)) * (1.f / 4095.f);
    float sd   = sqrtf(fmaxf(var, 0.f));
    float attn = 1.f / (1.f + expf(-(mean + sd)));
    float4* yp = (float4*)(y + (size_t)bo * HW);
#pragma unroll
    for (int i = 0; i < 4; ++i) {
        float4 v = yp[threadIdx.x + i * 256];
        v.x *= attn; v.y *= attn; v.z *= attn; v.w *= attn;
        yp[threadIdx.x + i * 256] = v;
    }
}

// ---------------------------------------------------------------------------
extern "C" void kernel_launch(void* const* d_in, const int* in_sizes, int n_in,
                              void* d_out, int out_size, void* d_ws, size_t ws_size,
                              hipStream_t stream)
{
    const float* x  = (const float*)d_in[0];   // [8,256,64,64]
    const float* ow = (const float*)d_in[1];   // [18,256,3,3]
    const float* dw = (const float*)d_in[2];   // [256,256,3,3]
    float* out = (float*)d_out;                // [8,256,64,64]
    float* ws  = (float*)d_ws;

    float*          offs = ws;                              // 589824 f
    unsigned short* xT   = (unsigned short*)(ws + 589824);  // 8388608 us
    short*          wR   = (short*)(xT + 8388608);          // 589824
    short*          wO   = wR + 589824;                     // 73728
    float*          sum_ = (float*)(wO + 73728);            // 2048
    float*          sumsq_ = sum_ + 2048;                   // 2048

    hipMemsetAsync(sum_, 0, 2 * 2048 * sizeof(float), stream);

    prep_weights_kernel<<<9 * 288, 256, 0, stream>>>(ow, dw, wR, wO);
    transpose_x_kernel<<<512, 256, 0, stream>>>(x, xT);
    offset_mfma_kernel<<<512, 256, 0, stream>>>(xT, wO, offs);
    deform_mfma_kernel<<<512, 512, 0, stream>>>(xT, offs, wR, out, sum_, sumsq_);
    attn_scale_kernel<<<2048, 256, 0, stream>>>(sum_, sumsq_, out);
}

// Round 13
// 197.599 us; speedup vs baseline: 1.1278x; 1.1278x over previous
//
#include <hip/hip_runtime.h>
#include <hip/hip_bf16.h>
#include <math.h>

#define C_IN 256
#define H_   64
#define W_   64
#define B_   8
#define COUT 256
#define HW   (H_*W_)

typedef float f32x4 __attribute__((ext_vector_type(4)));
typedef float f32x2 __attribute__((ext_vector_type(2)));
typedef short short8 __attribute__((ext_vector_type(8)));

static __device__ __forceinline__ int pack_bf16x2(float a, float b) {
    __hip_bfloat162 h = __float22bfloat162_rn(make_float2(a, b));
    union { __hip_bfloat162 h; int i; } u; u.h = h;
    return u.i;
}

// unpack bf16x2 word -> float2 (lo, hi)
static __device__ __forceinline__ f32x2 up2(int v) {
    union { int i; float f; } a, b;
    a.i = v << 16;
    b.i = v & 0xffff0000;
    f32x2 r; r[0] = a.f; r[1] = b.f;
    return r;
}

// ---------------------------------------------------------------------------
// Prep: weights -> bf16, laid out so a wave's MFMA A-fragment is ONE coalesced
// 1KB global load (no LDS staging needed).
//   wR: (k*8+cblk*2+ks)*8192 + oblk*512 + q*128 + ol*8 + ce    (o in 0..255)
//   wO: (k*8+cblk*2+ks)*1024 + oblk*512 + q*128 + ol*8 + ce    (o in 0..31)
// ---------------------------------------------------------------------------
__global__ __launch_bounds__(256) void prep_weights_kernel(
    const float* __restrict__ ow, const float* __restrict__ dw,
    short* __restrict__ wR, short* __restrict__ wO)
{
    int blk = blockIdx.x;
    int k   = blk / 288;
    int row = blk % 288;
    int c   = threadIdx.x;
    int cblk = c >> 6, ks = (c >> 5) & 1, q = (c >> 3) & 3, ce = c & 7;
    union { float f; unsigned u; } a;
    if (row < 256) {
        int o = row;
        a.f = dw[(size_t)o * 2304 + c * 9 + k];
        unsigned r = (a.u + 0x7fffu + ((a.u >> 16) & 1u)) >> 16;
        size_t idx = (size_t)(k * 8 + cblk * 2 + ks) * 8192
                   + (size_t)(o >> 4) * 512 + q * 128 + (o & 15) * 8 + ce;
        wR[idx] = (short)r;
    } else {
        int o = row - 256;                 // 0..31
        a.f = (o < 18) ? ow[(size_t)o * 2304 + c * 9 + k] : 0.f;
        unsigned r = (a.u + 0x7fffu + ((a.u >> 16) & 1u)) >> 16;
        size_t idx = (size_t)(k * 8 + cblk * 2 + ks) * 1024
                   + (size_t)(o >> 4) * 512 + q * 128 + (o & 15) * 8 + ce;
        wO[idx] = (short)r;
    }
}

// ---------------------------------------------------------------------------
// Transpose x: NCHW fp32 -> NHWC bf16  xT[b][h][w][c]. One block per (b,h).
// ---------------------------------------------------------------------------
__global__ __launch_bounds__(256) void transpose_x_kernel(
    const float* __restrict__ x, unsigned short* __restrict__ xT)
{
    __shared__ float tile[64][257];
    const int tid = threadIdx.x;
    const int b = blockIdx.x >> 6, h = blockIdx.x & 63;
    const float* xb = x + ((size_t)b << 20) + h * 64;

#pragma unroll
    for (int pass = 0; pass < 16; ++pass) {
        int c  = pass * 16 + (tid >> 4);
        int w0 = (tid & 15) * 4;
        float4 v = *(const float4*)(xb + (size_t)c * 4096 + w0);
        tile[w0][c] = v.x; tile[w0 + 1][c] = v.y;
        tile[w0 + 2][c] = v.z; tile[w0 + 3][c] = v.w;
    }
    __syncthreads();

    int4* ob = (int4*)(xT + ((size_t)blockIdx.x << 14));
#pragma unroll
    for (int pass = 0; pass < 8; ++pass) {
        int idx = pass * 256 + tid;
        int w = idx >> 5, ch8 = idx & 31;
        const float* tr = &tile[w][ch8 * 8];
        int4 pk;
        pk.x = pack_bf16x2(tr[0], tr[1]);
        pk.y = pack_bf16x2(tr[2], tr[3]);
        pk.z = pack_bf16x2(tr[4], tr[5]);
        pk.w = pack_bf16x2(tr[6], tr[7]);
        ob[idx] = pk;
    }
}

// ---------------------------------------------------------------------------
// Offset conv via bf16 MFMA — ROW-TILE chunk-major (r10-proven). One block
// per (b,ho). Stage rows ho-1..ho+1 x 64ch once per c-chunk (3 rows x 66
// px-slots, edge slots zeroed); all 9 taps read from the tile via slot
// shifts. 4 chunks, 8 barriers total, 36-MFMA clusters, loads for chunk c+1
// issued into named regs before MFMA(c) (sched_barrier pins issue order).
// ---------------------------------------------------------------------------
__global__ __launch_bounds__(256, 2) void offset_mfma_kernel(
    const unsigned short* __restrict__ xT, const short* __restrict__ wO,
    float* __restrict__ offs)
{
    __shared__ int4 xtile[3 * 66 * 8];     // 25.3 KB

    const int tid = threadIdx.x;
    const int b   = blockIdx.x & 7;        // XCD pin
    const int ho  = blockIdx.x >> 3;

    const int wv = tid >> 6;
    const int ln = tid & 63;
    const int lo = ln & 15;
    const int quad = ln >> 4;

    f32x4 acc[2];
    acc[0] = (f32x4){0.f, 0.f, 0.f, 0.f};
    acc[1] = (f32x4){0.f, 0.f, 0.f, 0.f};

    const unsigned short* xbb = xT + ((size_t)b << 20);
    const int4 zero4 = {0, 0, 0, 0};

    const int srow = tid >> 6;             // 0..3
    const int spx  = tid & 63;
    const int syy  = ho + srow - 1;
    const bool svalid = (srow < 3) && (syy >= 0) && (syy < 64);
    const int syc  = min(max(syy, 0), 63);
    const unsigned short* sbase = xbb + (((size_t)(syc * 64 + spx)) << 8);
    const int sslot = spx + 1;

#define OLOAD(CH, G)                                                          \
    if (srow < 3) {                                                           \
        const int4* sp_ = (const int4*)(sbase + (CH));                        \
        _Pragma("unroll")                                                     \
        for (int j = 0; j < 8; ++j) G[j] = sp_[j];                            \
    }
#define OCOMMIT(G)                                                            \
    if (srow < 3) {                                                           \
        _Pragma("unroll")                                                     \
        for (int j = 0; j < 8; ++j)                                           \
            xtile[(srow * 66 + sslot) * 8 + (j ^ (sslot & 7))]                \
                = svalid ? G[j] : zero4;                                      \
    }

    auto mfmaC = [&](int chunk) {
        __builtin_amdgcn_s_setprio(1);
#pragma unroll
        for (int ky = 0; ky < 3; ++ky) {
#pragma unroll
            for (int kx = 0; kx < 3; ++kx) {
#pragma unroll
                for (int ks = 0; ks < 2; ++ks) {
                    int ps = wv * 16 + lo + kx;
                    int cslot = (ks * 4 + quad) ^ (ps & 7);
                    short8 bfr = *(const short8*)&xtile[(ky * 66 + ps) * 8 + cslot];
                    const short* wkb = wO
                        + (size_t)((ky * 3 + kx) * 8 + chunk * 2 + ks) * 1024
                        + ln * 8;
#pragma unroll
                    for (int t = 0; t < 2; ++t) {
                        short8 afr = *(const short8*)(wkb + t * 512);
                        acc[t] = __builtin_amdgcn_mfma_f32_16x16x32_bf16(
                            afr, bfr, acc[t], 0, 0, 0);
                    }
                }
            }
        }
        __builtin_amdgcn_s_setprio(0);
    };

    int4 ga[8], gb[8];
    OLOAD(0, ga);
    OCOMMIT(ga);
    if (srow == 3 && (tid & 63) < 6) {     // zero edge slots 0 and 65, once
        int idx = tid & 63;
        int row_ = idx >> 1, s_ = (idx & 1) * 65;
#pragma unroll
        for (int j = 0; j < 8; ++j) xtile[(row_ * 66 + s_) * 8 + j] = zero4;
    }
    __syncthreads();

    OLOAD(64, gb);
    __builtin_amdgcn_sched_barrier(0);
    mfmaC(0);
    __syncthreads();
    OCOMMIT(gb);
    __syncthreads();

    OLOAD(128, ga);
    __builtin_amdgcn_sched_barrier(0);
    mfmaC(1);
    __syncthreads();
    OCOMMIT(ga);
    __syncthreads();

    OLOAD(192, gb);
    __builtin_amdgcn_sched_barrier(0);
    mfmaC(2);
    __syncthreads();
    OCOMMIT(gb);
    __syncthreads();

    mfmaC(3);
#undef OLOAD
#undef OCOMMIT

#pragma unroll
    for (int t = 0; t < 2; ++t) {
#pragma unroll
        for (int r = 0; r < 4; ++r) {
            int o = t * 16 + quad * 4 + r;
            if (o < 18)
                offs[((size_t)b * 18 + o) * HW + ho * 64 + wv * 16 + lo] = acc[t][r];
        }
    }
}

// ---------------------------------------------------------------------------
// Deformable conv. One block per (b, ho): grid 512, 64 px x 256 o.
// r5-exact schedule (best measured 66.9us): register dbuf of BOTH load
// streams — A-frags (wR) 1 stage ahead, gathers 2 stages ahead; per stage
// issue A(s+1) then G(s+2), sched_barrier, MFMA consumes A(s) (oldest
// outstanding batch -> counted vmcnt, no stall). ONE __syncthreads per stage.
// launch_bounds(256,2) is REQUIRED: tighter bounds make the register
// allocator sink the named prefetch into its uses (r1/r2/r7 collapse).
// ---------------------------------------------------------------------------
struct afrag { short8 v[2][4]; };

__global__ __launch_bounds__(256, 2) void deform_mfma_kernel(
    const unsigned short* __restrict__ xT, const float* __restrict__ offs,
    const short* __restrict__ wR, float* __restrict__ y,
    float* __restrict__ sum_, float* __restrict__ sumsq_)
{
    __shared__ int4   meta_i[576];
    __shared__ float4 meta_w[576];
    __shared__ int4   bT[2][64 * 8];

    const int tid = threadIdx.x;
    const int b   = blockIdx.x & 7;            // XCD pin
    const int ho  = blockIdx.x >> 3;

    for (int e = tid; e < 576; e += 256) {
        int kk  = e >> 6;
        int pxe = e & 63;
        float dy = offs[((size_t)b * 18 + 2 * kk)     * HW + ho * W_ + pxe];
        float dx = offs[((size_t)b * 18 + 2 * kk + 1) * HW + ho * W_ + pxe];
        float sy = (float)(ho - 1 + kk / 3) + dy;
        float sx = (float)(pxe - 1 + kk % 3) + dx;
        float y0f = floorf(sy), x0f = floorf(sx);
        float ly = sy - y0f, lx = sx - x0f;
        int y0 = (int)y0f, x0 = (int)x0f;
        int y1 = y0 + 1, x1 = x0 + 1;
        float wy0 = 1.f - ly, wx0 = 1.f - lx;
        bool vy0 = (y0 >= 0) & (y0 < H_), vy1 = (y1 >= 0) & (y1 < H_);
        bool vx0 = (x0 >= 0) & (x0 < W_), vx1 = (x1 >= 0) & (x1 < W_);
        int cy0 = min(max(y0, 0), H_ - 1), cy1 = min(max(y1, 0), H_ - 1);
        int cx0 = min(max(x0, 0), W_ - 1), cx1 = min(max(x1, 0), W_ - 1);
        int4 ii; float4 ww;
        ii.x = (cy0 * W_ + cx0) << 9;  ww.x = wy0 * wx0 * ((vy0 & vx0) ? 1.f : 0.f);
        ii.y = (cy0 * W_ + cx1) << 9;  ww.y = wy0 * lx  * ((vy0 & vx1) ? 1.f : 0.f);
        ii.z = (cy1 * W_ + cx0) << 9;  ww.z = ly  * wx0 * ((vy1 & vx0) ? 1.f : 0.f);
        ii.w = (cy1 * W_ + cx1) << 9;  ww.w = ly  * lx  * ((vy1 & vx1) ? 1.f : 0.f);
        meta_i[e] = ii;
        meta_w[e] = ww;
    }

    const int px = tid >> 2;        // 0..63
    const int cg = tid & 3;         // 16-ch group (32B = 2 int4 per corner)
    const int wv = tid >> 6;
    const int ln = tid & 63;
    const int lo = ln & 15;
    const int quad = ln >> 4;

    f32x4 acc[4][4];
#pragma unroll
    for (int t = 0; t < 4; ++t)
#pragma unroll
        for (int p = 0; p < 4; ++p)
            acc[t][p] = (f32x4){0.f, 0.f, 0.f, 0.f};

    const char* xbb = (const char*)(xT + ((size_t)b << 20) + cg * 16);

#define ISSUE_G(S, G0,G1,G2,G3,G4,G5,G6,G7)                                   \
    {                                                                         \
        int kn_ = (S) >> 2, cn_ = ((S) & 3) << 7;                             \
        int4 ii_ = meta_i[kn_ * 64 + px];                                     \
        const char* xc_ = xbb + cn_;                                          \
        const int4* pA_ = (const int4*)(xc_ + ii_.x);                         \
        const int4* pB_ = (const int4*)(xc_ + ii_.y);                         \
        const int4* pC_ = (const int4*)(xc_ + ii_.z);                         \
        const int4* pD_ = (const int4*)(xc_ + ii_.w);                         \
        G0 = pA_[0]; G1 = pA_[1];                                             \
        G2 = pB_[0]; G3 = pB_[1];                                             \
        G4 = pC_[0]; G5 = pC_[1];                                             \
        G6 = pD_[0]; G7 = pD_[1];                                             \
    }

#define ISSUE_A(S, AF)                                                        \
    {                                                                         \
        const short* wkb_ = wR + (size_t)((((S) >> 2) * 8 + ((S) & 3) * 2))   \
                          * 8192 + wv * 2048 + ln * 8;                        \
        _Pragma("unroll")                                                     \
        for (int ks_ = 0; ks_ < 2; ++ks_)                                     \
            _Pragma("unroll")                                                 \
            for (int t_ = 0; t_ < 4; ++t_)                                    \
                AF.v[ks_][t_] = *(const short8*)(wkb_ + ks_ * 8192 + t_ * 512);\
    }

#define BLEND_W(S, BUF, G0,G1,G2,G3,G4,G5,G6,G7)                              \
    {                                                                         \
        int kn_ = (S) >> 2;                                                   \
        float4 w4_ = meta_w[kn_ * 64 + px];                                   \
        auto bl_ = [&](int av, int bv, int cv, int dv) -> int {               \
            f32x2 r_ = up2(av) * w4_.x + up2(bv) * w4_.y                      \
                     + up2(cv) * w4_.z + up2(dv) * w4_.w;                     \
            return pack_bf16x2(r_[0], r_[1]);                                 \
        };                                                                    \
        int4 o0_, o1_;                                                        \
        o0_.x = bl_(G0.x, G2.x, G4.x, G6.x);                                  \
        o0_.y = bl_(G0.y, G2.y, G4.y, G6.y);                                  \
        o0_.z = bl_(G0.z, G2.z, G4.z, G6.z);                                  \
        o0_.w = bl_(G0.w, G2.w, G4.w, G6.w);                                  \
        o1_.x = bl_(G1.x, G3.x, G5.x, G7.x);                                  \
        o1_.y = bl_(G1.y, G3.y, G5.y, G7.y);                                  \
        o1_.z = bl_(G1.z, G3.z, G5.z, G7.z);                                  \
        o1_.w = bl_(G1.w, G3.w, G5.w, G7.w);                                  \
        bT[BUF][px * 8 + ((2 * cg)     ^ (px & 7))] = o0_;                    \
        bT[BUF][px * 8 + ((2 * cg + 1) ^ (px & 7))] = o1_;                    \
    }

    auto mfmaStage = [&](int buf, const afrag& AF) {
        __builtin_amdgcn_s_setprio(1);
#pragma unroll
        for (int ks = 0; ks < 2; ++ks) {
            int ch = ks * 4 + quad;
            short8 bfr[4];
#pragma unroll
            for (int p = 0; p < 4; ++p) {
                int pp = p * 16 + lo;
                bfr[p] = *(const short8*)&bT[buf][pp * 8 + (ch ^ (pp & 7))];
            }
#pragma unroll
            for (int t = 0; t < 4; ++t)
#pragma unroll
                for (int p = 0; p < 4; ++p)
                    acc[t][p] = __builtin_amdgcn_mfma_f32_16x16x32_bf16(
                        AF.v[ks][t], bfr[p], acc[t][p], 0, 0, 0);
        }
        __builtin_amdgcn_s_setprio(0);
    };

    int4 a0, a1, a2, a3, a4, a5, a6, a7;
    int4 b0, b1, b2, b3, b4, b5, b6, b7;
    afrag afrA, afrB;

    __syncthreads();                 // meta ready

    ISSUE_A(0, afrA);
    ISSUE_G(0, a0,a1,a2,a3,a4,a5,a6,a7);
    ISSUE_G(1, b0,b1,b2,b3,b4,b5,b6,b7);
    BLEND_W(0, 0, a0,a1,a2,a3,a4,a5,a6,a7);
    __syncthreads();

#pragma unroll 1
    for (int t = 0; t < 17; ++t) {
        int s = 2 * t;
        ISSUE_A(s + 1, afrB);
        ISSUE_G(s + 2, a0,a1,a2,a3,a4,a5,a6,a7);
        __builtin_amdgcn_sched_barrier(0);
        mfmaStage(0, afrA);
        BLEND_W(s + 1, 1, b0,b1,b2,b3,b4,b5,b6,b7);
        __syncthreads();
        ISSUE_A(s + 2, afrA);
        ISSUE_G(s + 3, b0,b1,b2,b3,b4,b5,b6,b7);
        __builtin_amdgcn_sched_barrier(0);
        mfmaStage(1, afrB);
        BLEND_W(s + 2, 0, a0,a1,a2,a3,a4,a5,a6,a7);
        __syncthreads();
    }
    // tail: afrA = A(34), b* = G(35), bT[0] holds stage 34
    ISSUE_A(35, afrB);
    __builtin_amdgcn_sched_barrier(0);
    mfmaStage(0, afrA);
    BLEND_W(35, 1, b0,b1,b2,b3,b4,b5,b6,b7);
    __syncthreads();
    mfmaStage(1, afrB);

#undef ISSUE_G
#undef ISSUE_A
#undef BLEND_W

    float* yb = y + ((size_t)b << 20) + ho * 64;
#pragma unroll
    for (int t = 0; t < 4; ++t) {
#pragma unroll
        for (int r = 0; r < 4; ++r) {
            int o = wv * 64 + t * 16 + quad * 4 + r;
            float sv = 0.f, qv = 0.f;
#pragma unroll
            for (int p = 0; p < 4; ++p) {
                float val = acc[t][p][r];
                yb[(size_t)o * HW + p * 16 + lo] = val;
                sv += val;
                qv += val * val;
            }
#pragma unroll
            for (int m = 1; m <= 8; m <<= 1) {
                sv += __shfl_xor(sv, m, 16);
                qv += __shfl_xor(qv, m, 16);
            }
            if (lo == 0) {
                atomicAdd(&sum_[b * COUT + o], sv);
                atomicAdd(&sumsq_[b * COUT + o], qv);
            }
        }
    }
}

// ---------------------------------------------------------------------------
// Channel attention (mean + unbiased std -> sigmoid) and scale.
// ---------------------------------------------------------------------------
__global__ __launch_bounds__(256) void attn_scale_kernel(
    const float* __restrict__ sum_, const float* __restrict__ sumsq_,
    float* __restrict__ y)
{
    int bo = blockIdx.x;
    float s = sum_[bo], q = sumsq_[bo];
    float mean = s * (1.f / 4096.f);
    float var  = (q - s * s * (1.f / 4096.f)) * (1.f / 4095.f);
    float sd   = sqrtf(fmaxf(var, 0.f));
    float attn = 1.f / (1.f + expf(-(mean + sd)));
    float4* yp = (float4*)(y + (size_t)bo * HW);
#pragma unroll
    for (int i = 0; i < 4; ++i) {
        float4 v = yp[threadIdx.x + i * 256];
        v.x *= attn; v.y *= attn; v.z *= attn; v.w *= attn;
        yp[threadIdx.x + i * 256] = v;
    }
}

// ---------------------------------------------------------------------------
extern "C" void kernel_launch(void* const* d_in, const int* in_sizes, int n_in,
                              void* d_out, int out_size, void* d_ws, size_t ws_size,
                              hipStream_t stream)
{
    const float* x  = (const float*)d_in[0];   // [8,256,64,64]
    const float* ow = (const float*)d_in[1];   // [18,256,3,3]
    const float* dw = (const float*)d_in[2];   // [256,256,3,3]
    float* out = (float*)d_out;                // [8,256,64,64]
    float* ws  = (float*)d_ws;

    float*          offs = ws;                              // 589824 f
    unsigned short* xT   = (unsigned short*)(ws + 589824);  // 8388608 us
    short*          wR   = (short*)(xT + 8388608);          // 589824
    short*          wO   = wR + 589824;                     // 73728
    float*          sum_ = (float*)(wO + 73728);            // 2048
    float*          sumsq_ = sum_ + 2048;                   // 2048

    hipMemsetAsync(sum_, 0, 2 * 2048 * sizeof(float), stream);

    prep_weights_kernel<<<9 * 288, 256, 0, stream>>>(ow, dw, wR, wO);
    transpose_x_kernel<<<512, 256, 0, stream>>>(x, xT);
    offset_mfma_kernel<<<512, 256, 0, stream>>>(xT, wO, offs);
    deform_mfma_kernel<<<512, 256, 0, stream>>>(xT, offs, wR, out, sum_, sumsq_);
    attn_scale_kernel<<<2048, 256, 0, stream>>>(sum_, sumsq_, out);
}

// Round 14
// 187.176 us; speedup vs baseline: 1.1906x; 1.0557x over previous
//
#include <hip/hip_runtime.h>
#include <hip/hip_bf16.h>
#include <math.h>

#define C_IN 256
#define H_   64
#define W_   64
#define B_   8
#define COUT 256
#define HW   (H_*W_)

typedef float f32x4 __attribute__((ext_vector_type(4)));
typedef float f32x2 __attribute__((ext_vector_type(2)));
typedef short short8 __attribute__((ext_vector_type(8)));

static __device__ __forceinline__ int pack_bf16x2(float a, float b) {
    __hip_bfloat162 h = __float22bfloat162_rn(make_float2(a, b));
    union { __hip_bfloat162 h; int i; } u; u.h = h;
    return u.i;
}

// unpack bf16x2 word -> float2 (lo, hi)
static __device__ __forceinline__ f32x2 up2(int v) {
    union { int i; float f; } a, b;
    a.i = v << 16;
    b.i = v & 0xffff0000;
    f32x2 r; r[0] = a.f; r[1] = b.f;
    return r;
}

// ---------------------------------------------------------------------------
// Prep: weights -> bf16, laid out so a wave's MFMA A-fragment is ONE coalesced
// 1KB global load (no LDS staging needed).
//   wR: (k*8+cblk*2+ks)*8192 + oblk*512 + q*128 + ol*8 + ce    (o in 0..255)
//   wO: (k*8+cblk*2+ks)*1024 + oblk*512 + q*128 + ol*8 + ce    (o in 0..31)
// ---------------------------------------------------------------------------
__global__ __launch_bounds__(256) void prep_weights_kernel(
    const float* __restrict__ ow, const float* __restrict__ dw,
    short* __restrict__ wR, short* __restrict__ wO)
{
    int blk = blockIdx.x;
    int k   = blk / 288;
    int row = blk % 288;
    int c   = threadIdx.x;
    int cblk = c >> 6, ks = (c >> 5) & 1, q = (c >> 3) & 3, ce = c & 7;
    union { float f; unsigned u; } a;
    if (row < 256) {
        int o = row;
        a.f = dw[(size_t)o * 2304 + c * 9 + k];
        unsigned r = (a.u + 0x7fffu + ((a.u >> 16) & 1u)) >> 16;
        size_t idx = (size_t)(k * 8 + cblk * 2 + ks) * 8192
                   + (size_t)(o >> 4) * 512 + q * 128 + (o & 15) * 8 + ce;
        wR[idx] = (short)r;
    } else {
        int o = row - 256;                 // 0..31
        a.f = (o < 18) ? ow[(size_t)o * 2304 + c * 9 + k] : 0.f;
        unsigned r = (a.u + 0x7fffu + ((a.u >> 16) & 1u)) >> 16;
        size_t idx = (size_t)(k * 8 + cblk * 2 + ks) * 1024
                   + (size_t)(o >> 4) * 512 + q * 128 + (o & 15) * 8 + ce;
        wO[idx] = (short)r;
    }
}

// ---------------------------------------------------------------------------
// Transpose x: NCHW fp32 -> NHWC bf16  xT[b][h][w][c]. One block per (b,h).
// ---------------------------------------------------------------------------
__global__ __launch_bounds__(256) void transpose_x_kernel(
    const float* __restrict__ x, unsigned short* __restrict__ xT)
{
    __shared__ float tile[64][257];
    const int tid = threadIdx.x;
    const int b = blockIdx.x >> 6, h = blockIdx.x & 63;
    const float* xb = x + ((size_t)b << 20) + h * 64;

#pragma unroll
    for (int pass = 0; pass < 16; ++pass) {
        int c  = pass * 16 + (tid >> 4);
        int w0 = (tid & 15) * 4;
        float4 v = *(const float4*)(xb + (size_t)c * 4096 + w0);
        tile[w0][c] = v.x; tile[w0 + 1][c] = v.y;
        tile[w0 + 2][c] = v.z; tile[w0 + 3][c] = v.w;
    }
    __syncthreads();

    int4* ob = (int4*)(xT + ((size_t)blockIdx.x << 14));
#pragma unroll
    for (int pass = 0; pass < 8; ++pass) {
        int idx = pass * 256 + tid;
        int w = idx >> 5, ch8 = idx & 31;
        const float* tr = &tile[w][ch8 * 8];
        int4 pk;
        pk.x = pack_bf16x2(tr[0], tr[1]);
        pk.y = pack_bf16x2(tr[2], tr[3]);
        pk.z = pack_bf16x2(tr[4], tr[5]);
        pk.w = pack_bf16x2(tr[6], tr[7]);
        ob[idx] = pk;
    }
}

// ---------------------------------------------------------------------------
// Offset conv via bf16 MFMA, NHWC input. One block per (b,ho), b = blk&7.
// A-fragments direct from global (coalesced layout); bT double-buffered;
// ONE barrier per stage. (r1-stageB version — every "improved" offset
// variant measured WORSE at the total: dbuf 214, tap-major ~150 others,
// row-tile 197-200. Totals with this one: 187.2 / 188.0.)
// ---------------------------------------------------------------------------
__global__ __launch_bounds__(256, 2) void offset_mfma_kernel(
    const unsigned short* __restrict__ xT, const short* __restrict__ wO,
    float* __restrict__ offs)
{
    __shared__ int4 bT[2][64 * 8];

    const int tid = threadIdx.x;
    const int b   = blockIdx.x & 7;        // XCD pin
    const int ho  = blockIdx.x >> 3;

    const int px = tid >> 2;               // 0..63
    const int cg = tid & 3;                // 16-ch group
    const int wv = tid >> 6;
    const int ln = tid & 63;
    const int lo = ln & 15;
    const int quad = ln >> 4;
    const int pxl = wv * 16 + lo;

    f32x4 acc[2];
    acc[0] = (f32x4){0.f, 0.f, 0.f, 0.f};
    acc[1] = (f32x4){0.f, 0.f, 0.f, 0.f};

    const unsigned short* xbb = xT + ((size_t)b << 20);
    const int4 zero4 = {0, 0, 0, 0};

    auto stageB = [&](int s, int buf) {
        int k = s >> 2, c0 = (s & 3) << 6;
        int yy = ho + k / 3 - 1;
        int xx = px + k % 3 - 1;
        bool valid = (yy >= 0) & (yy < 64) & (xx >= 0) & (xx < 64);
        int yc = min(max(yy, 0), 63), xc = min(max(xx, 0), 63);
        const int4* src = (const int4*)(xbb + (((size_t)yc * 64 + xc) << 8) + c0 + cg * 16);
        int4 p0 = valid ? src[0] : zero4;
        int4 p1 = valid ? src[1] : zero4;
        bT[buf][px * 8 + ((2 * cg)     ^ (px & 7))] = p0;
        bT[buf][px * 8 + ((2 * cg + 1) ^ (px & 7))] = p1;
    };

    stageB(0, 0);
    __syncthreads();

    for (int s = 0; s < 36; ++s) {
        const int cur = s & 1;
        if (s < 35) stageB(s + 1, cur ^ 1);

        const int k = s >> 2;
        const short* wkb = wO + (size_t)(k * 8 + (s & 3) * 2) * 1024 + ln * 8;
#pragma unroll
        for (int ks = 0; ks < 2; ++ks) {
            int ch = ks * 4 + quad;
            short8 bfr = *(const short8*)&bT[cur][pxl * 8 + (ch ^ (pxl & 7))];
#pragma unroll
            for (int t = 0; t < 2; ++t) {
                short8 afr = *(const short8*)(wkb + ks * 1024 + t * 512);
                acc[t] = __builtin_amdgcn_mfma_f32_16x16x32_bf16(afr, bfr, acc[t], 0, 0, 0);
            }
        }
        __syncthreads();
    }

#pragma unroll
    for (int t = 0; t < 2; ++t) {
#pragma unroll
        for (int r = 0; r < 4; ++r) {
            int o = t * 16 + quad * 4 + r;
            if (o < 18)
                offs[((size_t)b * 18 + o) * HW + ho * 64 + wv * 16 + lo] = acc[t][r];
        }
    }
}

// ---------------------------------------------------------------------------
// Deformable conv. One block per (b, ho): grid 512, 64 px x 256 o.
// r5-exact schedule (66.8us reproduced r13): register dbuf of BOTH load
// streams — A-frags (wR) 1 stage ahead, gathers 2 stages ahead; per stage
// issue A(s+1) then G(s+2), sched_barrier, MFMA consumes A(s) (oldest
// outstanding batch -> counted vmcnt, no stall). ONE __syncthreads per stage.
// launch_bounds(256,2) is REQUIRED: tighter bounds make the register
// allocator sink the named prefetch into its uses (r1/r2/r7 collapse).
// ---------------------------------------------------------------------------
struct afrag { short8 v[2][4]; };

__global__ __launch_bounds__(256, 2) void deform_mfma_kernel(
    const unsigned short* __restrict__ xT, const float* __restrict__ offs,
    const short* __restrict__ wR, float* __restrict__ y,
    float* __restrict__ sum_, float* __restrict__ sumsq_)
{
    __shared__ int4   meta_i[576];
    __shared__ float4 meta_w[576];
    __shared__ int4   bT[2][64 * 8];

    const int tid = threadIdx.x;
    const int b   = blockIdx.x & 7;            // XCD pin
    const int ho  = blockIdx.x >> 3;

    for (int e = tid; e < 576; e += 256) {
        int kk  = e >> 6;
        int pxe = e & 63;
        float dy = offs[((size_t)b * 18 + 2 * kk)     * HW + ho * W_ + pxe];
        float dx = offs[((size_t)b * 18 + 2 * kk + 1) * HW + ho * W_ + pxe];
        float sy = (float)(ho - 1 + kk / 3) + dy;
        float sx = (float)(pxe - 1 + kk % 3) + dx;
        float y0f = floorf(sy), x0f = floorf(sx);
        float ly = sy - y0f, lx = sx - x0f;
        int y0 = (int)y0f, x0 = (int)x0f;
        int y1 = y0 + 1, x1 = x0 + 1;
        float wy0 = 1.f - ly, wx0 = 1.f - lx;
        bool vy0 = (y0 >= 0) & (y0 < H_), vy1 = (y1 >= 0) & (y1 < H_);
        bool vx0 = (x0 >= 0) & (x0 < W_), vx1 = (x1 >= 0) & (x1 < W_);
        int cy0 = min(max(y0, 0), H_ - 1), cy1 = min(max(y1, 0), H_ - 1);
        int cx0 = min(max(x0, 0), W_ - 1), cx1 = min(max(x1, 0), W_ - 1);
        int4 ii; float4 ww;
        ii.x = (cy0 * W_ + cx0) << 9;  ww.x = wy0 * wx0 * ((vy0 & vx0) ? 1.f : 0.f);
        ii.y = (cy0 * W_ + cx1) << 9;  ww.y = wy0 * lx  * ((vy0 & vx1) ? 1.f : 0.f);
        ii.z = (cy1 * W_ + cx0) << 9;  ww.z = ly  * wx0 * ((vy1 & vx0) ? 1.f : 0.f);
        ii.w = (cy1 * W_ + cx1) << 9;  ww.w = ly  * lx  * ((vy1 & vx1) ? 1.f : 0.f);
        meta_i[e] = ii;
        meta_w[e] = ww;
    }

    const int px = tid >> 2;        // 0..63
    const int cg = tid & 3;         // 16-ch group (32B = 2 int4 per corner)
    const int wv = tid >> 6;
    const int ln = tid & 63;
    const int lo = ln & 15;
    const int quad = ln >> 4;

    f32x4 acc[4][4];
#pragma unroll
    for (int t = 0; t < 4; ++t)
#pragma unroll
        for (int p = 0; p < 4; ++p)
            acc[t][p] = (f32x4){0.f, 0.f, 0.f, 0.f};

    const char* xbb = (const char*)(xT + ((size_t)b << 20) + cg * 16);

#define ISSUE_G(S, G0,G1,G2,G3,G4,G5,G6,G7)                                   \
    {                                                                         \
        int kn_ = (S) >> 2, cn_ = ((S) & 3) << 7;                             \
        int4 ii_ = meta_i[kn_ * 64 + px];                                     \
        const char* xc_ = xbb + cn_;                                          \
        const int4* pA_ = (const int4*)(xc_ + ii_.x);                         \
        const int4* pB_ = (const int4*)(xc_ + ii_.y);                         \
        const int4* pC_ = (const int4*)(xc_ + ii_.z);                         \
        const int4* pD_ = (const int4*)(xc_ + ii_.w);                         \
        G0 = pA_[0]; G1 = pA_[1];                                             \
        G2 = pB_[0]; G3 = pB_[1];                                             \
        G4 = pC_[0]; G5 = pC_[1];                                             \
        G6 = pD_[0]; G7 = pD_[1];                                             \
    }

#define ISSUE_A(S, AF)                                                        \
    {                                                                         \
        const short* wkb_ = wR + (size_t)((((S) >> 2) * 8 + ((S) & 3) * 2))   \
                          * 8192 + wv * 2048 + ln * 8;                        \
        _Pragma("unroll")                                                     \
        for (int ks_ = 0; ks_ < 2; ++ks_)                                     \
            _Pragma("unroll")                                                 \
            for (int t_ = 0; t_ < 4; ++t_)                                    \
                AF.v[ks_][t_] = *(const short8*)(wkb_ + ks_ * 8192 + t_ * 512);\
    }

#define BLEND_W(S, BUF, G0,G1,G2,G3,G4,G5,G6,G7)                              \
    {                                                                         \
        int kn_ = (S) >> 2;                                                   \
        float4 w4_ = meta_w[kn_ * 64 + px];                                   \
        auto bl_ = [&](int av, int bv, int cv, int dv) -> int {               \
            f32x2 r_ = up2(av) * w4_.x + up2(bv) * w4_.y                      \
                     + up2(cv) * w4_.z + up2(dv) * w4_.w;                     \
            return pack_bf16x2(r_[0], r_[1]);                                 \
        };                                                                    \
        int4 o0_, o1_;                                                        \
        o0_.x = bl_(G0.x, G2.x, G4.x, G6.x);                                  \
        o0_.y = bl_(G0.y, G2.y, G4.y, G6.y);                                  \
        o0_.z = bl_(G0.z, G2.z, G4.z, G6.z);                                  \
        o0_.w = bl_(G0.w, G2.w, G4.w, G6.w);                                  \
        o1_.x = bl_(G1.x, G3.x, G5.x, G7.x);                                  \
        o1_.y = bl_(G1.y, G3.y, G5.y, G7.y);                                  \
        o1_.z = bl_(G1.z, G3.z, G5.z, G7.z);                                  \
        o1_.w = bl_(G1.w, G3.w, G5.w, G7.w);                                  \
        bT[BUF][px * 8 + ((2 * cg)     ^ (px & 7))] = o0_;                    \
        bT[BUF][px * 8 + ((2 * cg + 1) ^ (px & 7))] = o1_;                    \
    }

    auto mfmaStage = [&](int buf, const afrag& AF) {
        __builtin_amdgcn_s_setprio(1);
#pragma unroll
        for (int ks = 0; ks < 2; ++ks) {
            int ch = ks * 4 + quad;
            short8 bfr[4];
#pragma unroll
            for (int p = 0; p < 4; ++p) {
                int pp = p * 16 + lo;
                bfr[p] = *(const short8*)&bT[buf][pp * 8 + (ch ^ (pp & 7))];
            }
#pragma unroll
            for (int t = 0; t < 4; ++t)
#pragma unroll
                for (int p = 0; p < 4; ++p)
                    acc[t][p] = __builtin_amdgcn_mfma_f32_16x16x32_bf16(
                        AF.v[ks][t], bfr[p], acc[t][p], 0, 0, 0);
        }
        __builtin_amdgcn_s_setprio(0);
    };

    int4 a0, a1, a2, a3, a4, a5, a6, a7;
    int4 b0, b1, b2, b3, b4, b5, b6, b7;
    afrag afrA, afrB;

    __syncthreads();                 // meta ready

    ISSUE_A(0, afrA);
    ISSUE_G(0, a0,a1,a2,a3,a4,a5,a6,a7);
    ISSUE_G(1, b0,b1,b2,b3,b4,b5,b6,b7);
    BLEND_W(0, 0, a0,a1,a2,a3,a4,a5,a6,a7);
    __syncthreads();

#pragma unroll 1
    for (int t = 0; t < 17; ++t) {
        int s = 2 * t;
        ISSUE_A(s + 1, afrB);
        ISSUE_G(s + 2, a0,a1,a2,a3,a4,a5,a6,a7);
        __builtin_amdgcn_sched_barrier(0);
        mfmaStage(0, afrA);
        BLEND_W(s + 1, 1, b0,b1,b2,b3,b4,b5,b6,b7);
        __syncthreads();
        ISSUE_A(s + 2, afrA);
        ISSUE_G(s + 3, b0,b1,b2,b3,b4,b5,b6,b7);
        __builtin_amdgcn_sched_barrier(0);
        mfmaStage(1, afrB);
        BLEND_W(s + 2, 0, a0,a1,a2,a3,a4,a5,a6,a7);
        __syncthreads();
    }
    // tail: afrA = A(34), b* = G(35), bT[0] holds stage 34
    ISSUE_A(35, afrB);
    __builtin_amdgcn_sched_barrier(0);
    mfmaStage(0, afrA);
    BLEND_W(35, 1, b0,b1,b2,b3,b4,b5,b6,b7);
    __syncthreads();
    mfmaStage(1, afrB);

#undef ISSUE_G
#undef ISSUE_A
#undef BLEND_W

    float* yb = y + ((size_t)b << 20) + ho * 64;
#pragma unroll
    for (int t = 0; t < 4; ++t) {
#pragma unroll
        for (int r = 0; r < 4; ++r) {
            int o = wv * 64 + t * 16 + quad * 4 + r;
            float sv = 0.f, qv = 0.f;
#pragma unroll
            for (int p = 0; p < 4; ++p) {
                float val = acc[t][p][r];
                yb[(size_t)o * HW + p * 16 + lo] = val;
                sv += val;
                qv += val * val;
            }
#pragma unroll
            for (int m = 1; m <= 8; m <<= 1) {
                sv += __shfl_xor(sv, m, 16);
                qv += __shfl_xor(qv, m, 16);
            }
            if (lo == 0) {
                atomicAdd(&sum_[b * COUT + o], sv);
                atomicAdd(&sumsq_[b * COUT + o], qv);
            }
        }
    }
}

// ---------------------------------------------------------------------------
// Channel attention (mean + unbiased std -> sigmoid) and scale.
// ---------------------------------------------------------------------------
__global__ __launch_bounds__(256) void attn_scale_kernel(
    const float* __restrict__ sum_, const float* __restrict__ sumsq_,
    float* __restrict__ y)
{
    int bo = blockIdx.x;
    float s = sum_[bo], q = sumsq_[bo];
    float mean = s * (1.f / 4096.f);
    float var  = (q - s * s * (1.f / 4096.f)) * (1.f / 4095.f);
    float sd   = sqrtf(fmaxf(var, 0.f));
    float attn = 1.f / (1.f + expf(-(mean + sd)));
    float4* yp = (float4*)(y + (size_t)bo * HW);
#pragma unroll
    for (int i = 0; i < 4; ++i) {
        float4 v = yp[threadIdx.x + i * 256];
        v.x *= attn; v.y *= attn; v.z *= attn; v.w *= attn;
        yp[threadIdx.x + i * 256] = v;
    }
}

// ---------------------------------------------------------------------------
extern "C" void kernel_launch(void* const* d_in, const int* in_sizes, int n_in,
                              void* d_out, int out_size, void* d_ws, size_t ws_size,
                              hipStream_t stream)
{
    const float* x  = (const float*)d_in[0];   // [8,256,64,64]
    const float* ow = (const float*)d_in[1];   // [18,256,3,3]
    const float* dw = (const float*)d_in[2];   // [256,256,3,3]
    float* out = (float*)d_out;                // [8,256,64,64]
    float* ws  = (float*)d_ws;

    float*          offs = ws;                              // 589824 f
    unsigned short* xT   = (unsigned short*)(ws + 589824);  // 8388608 us
    short*          wR   = (short*)(xT + 8388608);          // 589824
    short*          wO   = wR + 589824;                     // 73728
    float*          sum_ = (float*)(wO + 73728);            // 2048
    float*          sumsq_ = sum_ + 2048;                   // 2048

    hipMemsetAsync(sum_, 0, 2 * 2048 * sizeof(float), stream);

    prep_weights_kernel<<<9 * 288, 256, 0, stream>>>(ow, dw, wR, wO);
    transpose_x_kernel<<<512, 256, 0, stream>>>(x, xT);
    offset_mfma_kernel<<<512, 256, 0, stream>>>(xT, wO, offs);
    deform_mfma_kernel<<<512, 256, 0, stream>>>(xT, offs, wR, out, sum_, sumsq_);
    attn_scale_kernel<<<2048, 256, 0, stream>>>(sum_, sumsq_, out);
}